// Round 7
// baseline (1547.399 us; speedup 1.0000x reference)
//
#include <hip/hip_runtime.h>

#define W 128
#define ROWS 32      // dst rows per block in fused_conv
#define BSHIFT 10    // 1024 dst ids per bucket
#define BSZ 1024

typedef short bf16x8 __attribute__((ext_vector_type(8)));
typedef float f32x4 __attribute__((ext_vector_type(4)));

__device__ __forceinline__ float lrelu(float x) { return x > 0.f ? x : 0.01f * x; }

// RTNE float -> bf16 (as ushort bit pattern)
__device__ __forceinline__ unsigned short f2bf(float f) {
    unsigned u = __float_as_uint(f);
    u += 0x7fffu + ((u >> 16) & 1u);
    return (unsigned short)(u >> 16);
}
__device__ __forceinline__ float bfu(unsigned short u) {
    return __uint_as_float(((unsigned)u) << 16);
}
// dword-level bf16 pair unpack: 1 VALU per channel
__device__ __forceinline__ float lo16(unsigned u) { return __uint_as_float(u << 16); }
__device__ __forceinline__ float hi16(unsigned u) { return __uint_as_float(u & 0xffff0000u); }
__device__ __forceinline__ unsigned pack2bf(float lo, float hi) {
    return (unsigned)f2bf(lo) | ((unsigned)f2bf(hi) << 16);
}
// unpack 8 bf16 channels from uint4 and min-accumulate
__device__ __forceinline__ void upmin8(float* mn, uint4 u) {
    mn[0] = fminf(mn[0], lo16(u.x)); mn[1] = fminf(mn[1], hi16(u.x));
    mn[2] = fminf(mn[2], lo16(u.y)); mn[3] = fminf(mn[3], hi16(u.y));
    mn[4] = fminf(mn[4], lo16(u.z)); mn[5] = fminf(mn[5], hi16(u.z));
    mn[6] = fminf(mn[6], lo16(u.w)); mn[7] = fminf(mn[7], hi16(u.w));
}

// ---- bucket-partitioned CSR build over concatenated dst domain ----
struct PairSrc {
    const int* d0; const int* s0; int n0;
    const int* d1; const int* s1; int n1;
    const int* d2; const int* s2; int n2;
    int NE, NF;
};

__device__ __forceinline__ void pair_at(const PairSrc& P, int g, int& dp, int& sp) {
    dp = -1; sp = 0;
    if (g < P.n0) { dp = P.d0[g]; sp = P.s0[g]; }
    else if (g < P.n0 + P.n1) { int j = g - P.n0; dp = P.NE + P.d1[j]; sp = P.s1[j]; }
    else if (g < P.n0 + P.n1 + P.n2) { int j = g - P.n0 - P.n1; dp = P.NE + P.NF + P.d2[j]; sp = P.s2[j]; }
}
// dst-only variant (halves part_hist read traffic)
__device__ __forceinline__ int pair_d(const PairSrc& P, int g) {
    if (g < P.n0) return P.d0[g];
    if (g < P.n0 + P.n1) return P.NE + P.d1[g - P.n0];
    if (g < P.n0 + P.n1 + P.n2) return P.NE + P.NF + P.d2[g - P.n0 - P.n1];
    return -1;
}

#define CHUNK 4096

// =====================================================================
// prep kernel: weight convert (512 blocks) + part_hist. Embeds are now
// fused into conv1/conv2 (their dst rows are block-contiguous) — the 77MB
// embed materialization + re-read is gone.
// =====================================================================
__global__ __launch_bounds__(256) void prep_kernel(
    const float* __restrict__ W0, const float* __restrict__ W1,
    const float* __restrict__ W2, const float* __restrict__ W3,
    unsigned short* __restrict__ T0, unsigned short* __restrict__ T1,
    unsigned short* __restrict__ T2, unsigned short* __restrict__ T3,
    PairSrc P, int* __restrict__ gcnt) {
    __shared__ int hist[512];
    int b = blockIdx.x;
    if (b < 512) {  // weight convert
        int which = b >> 7;
        const float* Wm = (which == 0) ? W0 : (which == 1) ? W1 : (which == 2) ? W2 : W3;
        unsigned short* Wt = (which == 0) ? T0 : (which == 1) ? T1 : (which == 2) ? T2 : T3;
        int i = (b & 127) * 256 + threadIdx.x;
        int k = i >> 7, n = i & 127;
        Wt[n * 256 + k] = f2bf(Wm[k * W + n]);
    } else {  // part_hist (dst-only reads)
        int hb = b - 512;
        int t = threadIdx.x;
        for (int j = t; j < 512; j += 256) hist[j] = 0;
        __syncthreads();
        int g0 = hb * CHUNK;
#pragma unroll
        for (int k = 0; k < 16; k++) {
            int dp = pair_d(P, g0 + k * 256 + t);
            if (dp >= 0) atomicAdd(&hist[dp >> BSHIFT], 1);
        }
        __syncthreads();
        for (int j = t; j < 512; j += 256)
            if (hist[j]) atomicAdd(&gcnt[j], hist[j]);
    }
}

__global__ void bucket_scan(const int* __restrict__ gcnt, int* __restrict__ goff,
                            int* __restrict__ gcur, int NB, int NP) {
    __shared__ int s[512];
    int t = threadIdx.x;
    int v = (t < NB) ? gcnt[t] : 0;
    s[t] = v;
    __syncthreads();
    for (int off = 1; off < 512; off <<= 1) {
        int add = (t >= off) ? s[t - off] : 0;
        __syncthreads();
        s[t] += add;
        __syncthreads();
    }
    if (t < NB) {
        int excl = s[t] - v;
        goff[t] = excl;
        gcur[t] = excl;
    }
    if (t == 0) goff[NB] = NP;
}

__global__ __launch_bounds__(256) void part_scatter(PairSrc P, int* __restrict__ gcur,
                                                    int2* __restrict__ pairs) {
    __shared__ int hist[512];
    __shared__ int base[512];
    int t = threadIdx.x;
    for (int j = t; j < 512; j += 256) hist[j] = 0;
    __syncthreads();
    int g0 = blockIdx.x * CHUNK;
    int dv[16], sv[16], rk[16];
#pragma unroll
    for (int k = 0; k < 16; k++) {
        pair_at(P, g0 + k * 256 + t, dv[k], sv[k]);
        rk[k] = (dv[k] >= 0) ? atomicAdd(&hist[dv[k] >> BSHIFT], 1) : 0;
    }
    __syncthreads();
    for (int j = t; j < 512; j += 256)
        base[j] = hist[j] ? atomicAdd(&gcur[j], hist[j]) : 0;
    __syncthreads();
#pragma unroll
    for (int k = 0; k < 16; k++) {
        if (dv[k] >= 0) pairs[base[dv[k] >> BSHIFT] + rk[k]] = make_int2(dv[k], sv[k]);
    }
}

// one block per bucket: LDS counting sort -> rowptr + ci (src only)
__global__ __launch_bounds__(256) void bucket_sort(const int2* __restrict__ pairs,
                                                   const int* __restrict__ goff, int D, int NP,
                                                   int* __restrict__ rowptr,
                                                   int* __restrict__ ci) {
    __shared__ int hist[BSZ];
    __shared__ int base[BSZ];
    __shared__ int tsum[256];
    int b = blockIdx.x, t = threadIdx.x;
    int d0 = b << BSHIFT;
    int roff = goff[b], rend = goff[b + 1], cnt = rend - roff;
    for (int j = t; j < BSZ; j += 256) hist[j] = 0;
    __syncthreads();
    for (int i = t; i < cnt; i += 256) {
        int2 pr = pairs[roff + i];
        atomicAdd(&hist[pr.x - d0], 1);
    }
    __syncthreads();
    int loc[4], s0 = 0;
#pragma unroll
    for (int k = 0; k < 4; k++) {
        loc[k] = s0;
        s0 += hist[t * 4 + k];
    }
    tsum[t] = s0;
    __syncthreads();
    for (int off = 1; off < 256; off <<= 1) {
        int add = (t >= off) ? tsum[t - off] : 0;
        __syncthreads();
        tsum[t] += add;
        __syncthreads();
    }
    int ebase = tsum[t] - s0;
#pragma unroll
    for (int k = 0; k < 4; k++) base[t * 4 + k] = ebase + loc[k];
    __syncthreads();
    for (int j = t; j < BSZ; j += 256) {
        int d = d0 + j;
        if (d < D) rowptr[d] = roff + base[j];
    }
    if (b == 0 && t == 0) rowptr[D] = NP;
    if (b == 0 && t < 8) ci[NP + t] = 0;  // zero pad: clamped prefetch beyond NP is safe
    for (int j = t; j < BSZ; j += 256) hist[j] = base[j];
    __syncthreads();
    for (int i = t; i < cnt; i += 256) {
        int2 pr = pairs[roff + i];
        int pos = roff + atomicAdd(&hist[pr.x - d0], 1);
        ci[pos] = pr.y;
    }
}

// ---- shared MFMA MLP + residual epilogue; output staged in LDS for
//      fully-coalesced 16B-lane stores ----
template <bool OUT_F32>
__device__ __forceinline__ void mlp_epilogue(
    unsigned short* h, const unsigned short* __restrict__ Wt,
    const float* __restrict__ bias, unsigned short* __restrict__ out_b,
    float* __restrict__ out_f, int r0, int n_dst, int wave, int lane, int tid) {
    int rt = wave >> 1;
    int ctbase = (wave & 1) * 4;
    int m = lane & 15, q = lane >> 4;
    f32x4 acc[4];
#pragma unroll
    for (int ct = 0; ct < 4; ct++) acc[ct] = (f32x4){0.f, 0.f, 0.f, 0.f};
    for (int k0 = 0; k0 < 256; k0 += 32) {
        bf16x8 a = *(const bf16x8*)&h[(rt * 16 + m) * 264 + k0 + q * 8];
#pragma unroll
        for (int ct = 0; ct < 4; ct++) {
            int n = (ctbase + ct) * 16 + m;
            bf16x8 b = *(const bf16x8*)&Wt[n * 256 + k0 + q * 8];
            acc[ct] = __builtin_amdgcn_mfma_f32_16x16x32_bf16(a, b, acc[ct], 0, 0, 0);
        }
    }
    // residual + activation into acc (reads h; no h writes yet)
#pragma unroll
    for (int ct = 0; ct < 4; ct++) {
        int col = (ctbase + ct) * 16 + m;
        float bc = bias[col];
#pragma unroll
        for (int reg = 0; reg < 4; reg++) {
            int r_l = rt * 16 + q * 4 + reg;
            acc[ct][reg] = bfu(h[r_l * 264 + col]) + lrelu(acc[ct][reg] + bc);
        }
    }
    __syncthreads();  // all reads of h complete
    if (OUT_F32) {
        float* hf = (float*)h;  // compact [32][128] f32 tile
#pragma unroll
        for (int ct = 0; ct < 4; ct++) {
            int col = (ctbase + ct) * 16 + m;
#pragma unroll
            for (int reg = 0; reg < 4; reg++) {
                int r_l = rt * 16 + q * 4 + reg;
                hf[r_l * 128 + col] = acc[ct][reg];
            }
        }
    } else {
        unsigned short* hs = h;  // compact [32][128] bf16 tile
#pragma unroll
        for (int ct = 0; ct < 4; ct++) {
            int col = (ctbase + ct) * 16 + m;
#pragma unroll
            for (int reg = 0; reg < 4; reg++) {
                int r_l = rt * 16 + q * 4 + reg;
                hs[r_l * 128 + col] = f2bf(acc[ct][reg]);
            }
        }
    }
    __syncthreads();
    if (OUT_F32) {
        const uint4* hv = (const uint4*)h;  // 32 rows x 32 uint4
        for (int i = tid; i < 1024; i += 256) {
            int r_l = i >> 5;
            int row = r0 + r_l;
            if (row < n_dst) ((uint4*)out_f)[(size_t)row * 32 + (i & 31)] = hv[i];
        }
    } else {
        const uint4* hv = (const uint4*)h;  // 32 rows x 16 uint4
        for (int i = tid; i < 512; i += 256) {
            int r_l = i >> 4;
            int row = r0 + r_l;
            if (row < n_dst) ((uint4*)out_b)[(size_t)row * 16 + (i & 15)] = hv[i];
        }
    }
}

// =====================================================================
// fused conv, ROW-parallel; EK>0: dst embed computed in-kernel from raw
// features (dst rows are block-contiguous; embed weights in LDS), so no
// embed materialization pass. EK==0: dst rows loaded from xdb (bf16).
// Embed is computed BEFORE issuing the 16 payload gathers so the rv/acc
// registers retire before the 64-VGPR payload goes live (VGPR<=128).
// =====================================================================
template <int EK, bool OUT_F32>
__global__ __launch_bounds__(256, 4) void fused_conv_rp(
    const unsigned short* __restrict__ xsb, const unsigned short* __restrict__ xdb,
    const float* __restrict__ draw, const float* __restrict__ Wd, const float* __restrict__ bd,
    unsigned short* __restrict__ out_b, float* __restrict__ out_f,
    const int* __restrict__ rowptr, const int* __restrict__ ci,
    const unsigned short* __restrict__ Wt, const float* __restrict__ bias, int n_dst) {
    __shared__ unsigned short h[ROWS * 264];  // [32 rows][256 + 8 pad] bf16
    __shared__ float wl[(EK > 0 ? EK : 1) * W];
    __shared__ float bl[W];
    int t = threadIdx.x;
    int wave = t >> 6, lane = t & 63;
    int grp = t >> 4;        // 0..15, owns rows {2*grp, 2*grp+1}
    int li16 = t & 15;       // 16B slot within 256B row
    int r0 = blockIdx.x * ROWS;
    int rbase = grp * 2;
    const uint4* xs4 = (const uint4*)xsb;

    if (EK > 0) {
        for (int i = t; i < EK * W; i += 256) wl[i] = Wd[i];
        if (t < W) bl[t] = bd[t];
        __syncthreads();
    }

    int dA = r0 + rbase, dB = dA + 1;
    int sA = 0, dgA = 0, sB = 0, dgB = 0;
    if (dA < n_dst) { sA = rowptr[dA]; dgA = rowptr[dA + 1] - sA; }
    if (dB < n_dst) { sB = rowptr[dB]; dgB = rowptr[dB + 1] - sB; }
    int mA = dgA - 1; if (mA < 0) mA = 0;
    int mB = dgB - 1; if (mB < 0) mB = 0;

    // window-1 indices for both rows (clamped; dup gathers hit L1)
    int idxA[8], idxB[8];
#pragma unroll
    for (int k = 0; k < 8; k++) { int o = k > mA ? mA : k; idxA[k] = ci[sA + o]; }
#pragma unroll
    for (int k = 0; k < 8; k++) { int o = k > mB ? mB : k; idxB[k] = ci[sB + o]; }

    // ---- dst rows: computed embed (EK>0) or bf16 load (EK==0)
    uint4 xdvA = make_uint4(0, 0, 0, 0), xdvB = make_uint4(0, 0, 0, 0);
    if (EK > 0) {
        const int EKX = EK > 0 ? EK : 1;
        float rvA[EKX], rvB[EKX];
#pragma unroll
        for (int k = 0; k < EK; k++) rvA[k] = (dA < n_dst) ? draw[(size_t)dA * EK + k] : 0.f;
#pragma unroll
        for (int k = 0; k < EK; k++) rvB[k] = (dB < n_dst) ? draw[(size_t)dB * EK + k] : 0.f;
        int ch0 = li16 * 8;
        float sa[8], sb[8];
#pragma unroll
        for (int j = 0; j < 8; j++) { sa[j] = bl[ch0 + j]; sb[j] = sa[j]; }
#pragma unroll
        for (int k = 0; k < EK; k++) {
            float4 wa = *(const float4*)&wl[k * W + ch0];
            float4 wb = *(const float4*)&wl[k * W + ch0 + 4];
            sa[0] += rvA[k] * wa.x; sa[1] += rvA[k] * wa.y; sa[2] += rvA[k] * wa.z; sa[3] += rvA[k] * wa.w;
            sa[4] += rvA[k] * wb.x; sa[5] += rvA[k] * wb.y; sa[6] += rvA[k] * wb.z; sa[7] += rvA[k] * wb.w;
            sb[0] += rvB[k] * wa.x; sb[1] += rvB[k] * wa.y; sb[2] += rvB[k] * wa.z; sb[3] += rvB[k] * wa.w;
            sb[4] += rvB[k] * wb.x; sb[5] += rvB[k] * wb.y; sb[6] += rvB[k] * wb.z; sb[7] += rvB[k] * wb.w;
        }
        xdvA = make_uint4(pack2bf(lrelu(sa[0]), lrelu(sa[1])), pack2bf(lrelu(sa[2]), lrelu(sa[3])),
                          pack2bf(lrelu(sa[4]), lrelu(sa[5])), pack2bf(lrelu(sa[6]), lrelu(sa[7])));
        xdvB = make_uint4(pack2bf(lrelu(sb[0]), lrelu(sb[1])), pack2bf(lrelu(sb[2]), lrelu(sb[3])),
                          pack2bf(lrelu(sb[4]), lrelu(sb[5])), pack2bf(lrelu(sb[6]), lrelu(sb[7])));
    } else {
        const uint4* xd4 = (const uint4*)xdb;
        if (dA < n_dst) xdvA = xd4[(size_t)dA * 16 + li16];
        if (dB < n_dst) xdvB = xd4[(size_t)dB * 16 + li16];
    }

    // issue all 16 window-1 gathers before any consumption
    uint4 a0 = xs4[(size_t)idxA[0] * 16 + li16], a1 = xs4[(size_t)idxA[1] * 16 + li16];
    uint4 a2 = xs4[(size_t)idxA[2] * 16 + li16], a3 = xs4[(size_t)idxA[3] * 16 + li16];
    uint4 a4 = xs4[(size_t)idxA[4] * 16 + li16], a5 = xs4[(size_t)idxA[5] * 16 + li16];
    uint4 a6 = xs4[(size_t)idxA[6] * 16 + li16], a7 = xs4[(size_t)idxA[7] * 16 + li16];
    uint4 b0 = xs4[(size_t)idxB[0] * 16 + li16], b1 = xs4[(size_t)idxB[1] * 16 + li16];
    uint4 b2 = xs4[(size_t)idxB[2] * 16 + li16], b3 = xs4[(size_t)idxB[3] * 16 + li16];
    uint4 b4 = xs4[(size_t)idxB[4] * 16 + li16], b5 = xs4[(size_t)idxB[5] * 16 + li16];
    uint4 b6 = xs4[(size_t)idxB[6] * 16 + li16], b7 = xs4[(size_t)idxB[7] * 16 + li16];

    // window-2 indices prefetch (only used if deg>8; clamp keeps them safe)
    int idxA2[8], idxB2[8];
#pragma unroll
    for (int k = 0; k < 8; k++) { int o = 8 + k; o = o > mA ? mA : o; idxA2[k] = ci[sA + o]; }
#pragma unroll
    for (int k = 0; k < 8; k++) { int o = 8 + k; o = o > mB ? mB : o; idxB2[k] = ci[sB + o]; }

    // ---- reduce row A
    {
        float mn[8];
#pragma unroll
        for (int k = 0; k < 8; k++) mn[k] = 1e30f;
        upmin8(mn, a0); upmin8(mn, a1); upmin8(mn, a2); upmin8(mn, a3);
        upmin8(mn, a4); upmin8(mn, a5); upmin8(mn, a6); upmin8(mn, a7);
        if (dgA > 8) {
            uint4 v0 = xs4[(size_t)idxA2[0] * 16 + li16], v1 = xs4[(size_t)idxA2[1] * 16 + li16];
            uint4 v2 = xs4[(size_t)idxA2[2] * 16 + li16], v3 = xs4[(size_t)idxA2[3] * 16 + li16];
            uint4 v4 = xs4[(size_t)idxA2[4] * 16 + li16], v5 = xs4[(size_t)idxA2[5] * 16 + li16];
            uint4 v6 = xs4[(size_t)idxA2[6] * 16 + li16], v7 = xs4[(size_t)idxA2[7] * 16 + li16];
            upmin8(mn, v0); upmin8(mn, v1); upmin8(mn, v2); upmin8(mn, v3);
            upmin8(mn, v4); upmin8(mn, v5); upmin8(mn, v6); upmin8(mn, v7);
            int c = 16;
            while (c < dgA) {  // rare (deg>16)
                int id[8];
#pragma unroll
                for (int k = 0; k < 8; k++) { int o = c + k; o = o > mA ? mA : o; id[k] = ci[sA + o]; }
                uint4 w0 = xs4[(size_t)id[0] * 16 + li16], w1 = xs4[(size_t)id[1] * 16 + li16];
                uint4 w2 = xs4[(size_t)id[2] * 16 + li16], w3 = xs4[(size_t)id[3] * 16 + li16];
                uint4 w4 = xs4[(size_t)id[4] * 16 + li16], w5 = xs4[(size_t)id[5] * 16 + li16];
                uint4 w6 = xs4[(size_t)id[6] * 16 + li16], w7 = xs4[(size_t)id[7] * 16 + li16];
                upmin8(mn, w0); upmin8(mn, w1); upmin8(mn, w2); upmin8(mn, w3);
                upmin8(mn, w4); upmin8(mn, w5); upmin8(mn, w6); upmin8(mn, w7);
                c += 8;
            }
        }
        float m0 = dgA ? lo16(xdvA.x) - mn[0] : 0.f, m1 = dgA ? hi16(xdvA.x) - mn[1] : 0.f;
        float m2 = dgA ? lo16(xdvA.y) - mn[2] : 0.f, m3 = dgA ? hi16(xdvA.y) - mn[3] : 0.f;
        float m4 = dgA ? lo16(xdvA.z) - mn[4] : 0.f, m5 = dgA ? hi16(xdvA.z) - mn[5] : 0.f;
        float m6 = dgA ? lo16(xdvA.w) - mn[6] : 0.f, m7 = dgA ? hi16(xdvA.w) - mn[7] : 0.f;
        uint4 mxp = make_uint4(pack2bf(m0, m1), pack2bf(m2, m3), pack2bf(m4, m5), pack2bf(m6, m7));
        *(uint4*)&h[rbase * 264 + li16 * 8] = xdvA;
        *(uint4*)&h[rbase * 264 + 128 + li16 * 8] = mxp;
    }
    // ---- reduce row B
    {
        float mn[8];
#pragma unroll
        for (int k = 0; k < 8; k++) mn[k] = 1e30f;
        upmin8(mn, b0); upmin8(mn, b1); upmin8(mn, b2); upmin8(mn, b3);
        upmin8(mn, b4); upmin8(mn, b5); upmin8(mn, b6); upmin8(mn, b7);
        if (dgB > 8) {
            uint4 v0 = xs4[(size_t)idxB2[0] * 16 + li16], v1 = xs4[(size_t)idxB2[1] * 16 + li16];
            uint4 v2 = xs4[(size_t)idxB2[2] * 16 + li16], v3 = xs4[(size_t)idxB2[3] * 16 + li16];
            uint4 v4 = xs4[(size_t)idxB2[4] * 16 + li16], v5 = xs4[(size_t)idxB2[5] * 16 + li16];
            uint4 v6 = xs4[(size_t)idxB2[6] * 16 + li16], v7 = xs4[(size_t)idxB2[7] * 16 + li16];
            upmin8(mn, v0); upmin8(mn, v1); upmin8(mn, v2); upmin8(mn, v3);
            upmin8(mn, v4); upmin8(mn, v5); upmin8(mn, v6); upmin8(mn, v7);
            int c = 16;
            while (c < dgB) {
                int id[8];
#pragma unroll
                for (int k = 0; k < 8; k++) { int o = c + k; o = o > mB ? mB : o; id[k] = ci[sB + o]; }
                uint4 w0 = xs4[(size_t)id[0] * 16 + li16], w1 = xs4[(size_t)id[1] * 16 + li16];
                uint4 w2 = xs4[(size_t)id[2] * 16 + li16], w3 = xs4[(size_t)id[3] * 16 + li16];
                uint4 w4 = xs4[(size_t)id[4] * 16 + li16], w5 = xs4[(size_t)id[5] * 16 + li16];
                uint4 w6 = xs4[(size_t)id[6] * 16 + li16], w7 = xs4[(size_t)id[7] * 16 + li16];
                upmin8(mn, w0); upmin8(mn, w1); upmin8(mn, w2); upmin8(mn, w3);
                upmin8(mn, w4); upmin8(mn, w5); upmin8(mn, w6); upmin8(mn, w7);
                c += 8;
            }
        }
        float m0 = dgB ? lo16(xdvB.x) - mn[0] : 0.f, m1 = dgB ? hi16(xdvB.x) - mn[1] : 0.f;
        float m2 = dgB ? lo16(xdvB.y) - mn[2] : 0.f, m3 = dgB ? hi16(xdvB.y) - mn[3] : 0.f;
        float m4 = dgB ? lo16(xdvB.z) - mn[4] : 0.f, m5 = dgB ? hi16(xdvB.z) - mn[5] : 0.f;
        float m6 = dgB ? lo16(xdvB.w) - mn[6] : 0.f, m7 = dgB ? hi16(xdvB.w) - mn[7] : 0.f;
        uint4 mxp = make_uint4(pack2bf(m0, m1), pack2bf(m2, m3), pack2bf(m4, m5), pack2bf(m6, m7));
        *(uint4*)&h[(rbase + 1) * 264 + li16 * 8] = xdvB;
        *(uint4*)&h[(rbase + 1) * 264 + 128 + li16 * 8] = mxp;
    }
    __syncthreads();
    mlp_epilogue<OUT_F32>(h, Wt, bias, out_b, out_f, r0, n_dst, wave, lane, t);
}

// =====================================================================
// V2E conv: src = raw 12B vertex gather + in-register vertex embed
// (L2-resident table); dst = edge embed computed in-kernel (We in LDS).
// No embed materialization anywhere.
// =====================================================================
__global__ __launch_bounds__(256, 4) void fused_conv_v2e_rp(
    const float* __restrict__ verts, const float* __restrict__ Wv, const float* __restrict__ bv,
    const float* __restrict__ edges, const float* __restrict__ We, const float* __restrict__ be,
    unsigned short* __restrict__ x_eb, const int* __restrict__ rowptr,
    const int* __restrict__ ci,
    const unsigned short* __restrict__ Wt, const float* __restrict__ bias, int n_dst) {
    __shared__ unsigned short h[ROWS * 264];
    __shared__ float wl[12 * W];
    __shared__ float bl[W];
    int t = threadIdx.x;
    int wave = t >> 6, lane = t & 63;
    int grp = t >> 4;
    int li16 = t & 15;
    int r0 = blockIdx.x * ROWS;
    int rbase = grp * 2;

    for (int i = t; i < 12 * W; i += 256) wl[i] = We[i];
    if (t < W) bl[t] = be[t];
    __syncthreads();

    // this lane's 8-channel slice of the vertex embed weights
    float4 w0a = *(const float4*)&Wv[0 * W + li16 * 8], w0b = *(const float4*)&Wv[0 * W + li16 * 8 + 4];
    float4 w1a = *(const float4*)&Wv[1 * W + li16 * 8], w1b = *(const float4*)&Wv[1 * W + li16 * 8 + 4];
    float4 w2a = *(const float4*)&Wv[2 * W + li16 * 8], w2b = *(const float4*)&Wv[2 * W + li16 * 8 + 4];
    float4 bva = *(const float4*)&bv[li16 * 8],         bvb = *(const float4*)&bv[li16 * 8 + 4];

    int dA = r0 + rbase, dB = dA + 1;
    int sA = 0, dgA = 0, sB = 0, dgB = 0;
    if (dA < n_dst) { sA = rowptr[dA]; dgA = rowptr[dA + 1] - sA; }
    if (dB < n_dst) { sB = rowptr[dB]; dgB = rowptr[dB + 1] - sB; }
    int mA = dgA - 1; if (mA < 0) mA = 0;
    int mB = dgB - 1; if (mB < 0) mB = 0;

    int idxA[4], idxB[4];
#pragma unroll
    for (int k = 0; k < 4; k++) { int o = k > mA ? mA : k; idxA[k] = ci[sA + o]; }
#pragma unroll
    for (int k = 0; k < 4; k++) { int o = k > mB ? mB : k; idxB[k] = ci[sB + o]; }

    // issue src vertex loads (broadcast within group)
    float vA[4][3], vB[4][3];
#pragma unroll
    for (int k = 0; k < 4; k++) {
        vA[k][0] = verts[3 * idxA[k]]; vA[k][1] = verts[3 * idxA[k] + 1]; vA[k][2] = verts[3 * idxA[k] + 2];
    }
#pragma unroll
    for (int k = 0; k < 4; k++) {
        vB[k][0] = verts[3 * idxB[k]]; vB[k][1] = verts[3 * idxB[k] + 1]; vB[k][2] = verts[3 * idxB[k] + 2];
    }

    // ---- dst edge embed (K=12, weights in LDS), under src-load latency
    uint4 xdvA, xdvB;
    {
        float rvA[12], rvB[12];
#pragma unroll
        for (int k = 0; k < 12; k++) rvA[k] = (dA < n_dst) ? edges[(size_t)dA * 12 + k] : 0.f;
#pragma unroll
        for (int k = 0; k < 12; k++) rvB[k] = (dB < n_dst) ? edges[(size_t)dB * 12 + k] : 0.f;
        int ch0 = li16 * 8;
        float sa[8], sb[8];
#pragma unroll
        for (int j = 0; j < 8; j++) { sa[j] = bl[ch0 + j]; sb[j] = sa[j]; }
#pragma unroll
        for (int k = 0; k < 12; k++) {
            float4 wa = *(const float4*)&wl[k * W + ch0];
            float4 wb = *(const float4*)&wl[k * W + ch0 + 4];
            sa[0] += rvA[k] * wa.x; sa[1] += rvA[k] * wa.y; sa[2] += rvA[k] * wa.z; sa[3] += rvA[k] * wa.w;
            sa[4] += rvA[k] * wb.x; sa[5] += rvA[k] * wb.y; sa[6] += rvA[k] * wb.z; sa[7] += rvA[k] * wb.w;
            sb[0] += rvB[k] * wa.x; sb[1] += rvB[k] * wa.y; sb[2] += rvB[k] * wa.z; sb[3] += rvB[k] * wa.w;
            sb[4] += rvB[k] * wb.x; sb[5] += rvB[k] * wb.y; sb[6] += rvB[k] * wb.z; sb[7] += rvB[k] * wb.w;
        }
        xdvA = make_uint4(pack2bf(lrelu(sa[0]), lrelu(sa[1])), pack2bf(lrelu(sa[2]), lrelu(sa[3])),
                          pack2bf(lrelu(sa[4]), lrelu(sa[5])), pack2bf(lrelu(sa[6]), lrelu(sa[7])));
        xdvB = make_uint4(pack2bf(lrelu(sb[0]), lrelu(sb[1])), pack2bf(lrelu(sb[2]), lrelu(sb[3])),
                          pack2bf(lrelu(sb[4]), lrelu(sb[5])), pack2bf(lrelu(sb[6]), lrelu(sb[7])));
    }

#pragma unroll
    for (int rr = 0; rr < 2; rr++) {
        int dg = (rr == 0) ? dgA : dgB;
        int sV = (rr == 0) ? sA : sB;
        int mV = (rr == 0) ? mA : mB;
        uint4 xdv = (rr == 0) ? xdvA : xdvB;
        float mn[8];
#pragma unroll
        for (int k = 0; k < 8; k++) mn[k] = 1e30f;
#pragma unroll
        for (int k = 0; k < 4; k++) {
            float a0 = (rr == 0) ? vA[k][0] : vB[k][0];
            float a1 = (rr == 0) ? vA[k][1] : vB[k][1];
            float a2 = (rr == 0) ? vA[k][2] : vB[k][2];
            float e0 = lrelu(bva.x + a0 * w0a.x + a1 * w1a.x + a2 * w2a.x);
            float e1 = lrelu(bva.y + a0 * w0a.y + a1 * w1a.y + a2 * w2a.y);
            float e2 = lrelu(bva.z + a0 * w0a.z + a1 * w1a.z + a2 * w2a.z);
            float e3 = lrelu(bva.w + a0 * w0a.w + a1 * w1a.w + a2 * w2a.w);
            float e4 = lrelu(bvb.x + a0 * w0b.x + a1 * w1b.x + a2 * w2b.x);
            float e5 = lrelu(bvb.y + a0 * w0b.y + a1 * w1b.y + a2 * w2b.y);
            float e6 = lrelu(bvb.z + a0 * w0b.z + a1 * w1b.z + a2 * w2b.z);
            float e7 = lrelu(bvb.w + a0 * w0b.w + a1 * w1b.w + a2 * w2b.w);
            mn[0] = fminf(mn[0], e0); mn[1] = fminf(mn[1], e1);
            mn[2] = fminf(mn[2], e2); mn[3] = fminf(mn[3], e3);
            mn[4] = fminf(mn[4], e4); mn[5] = fminf(mn[5], e5);
            mn[6] = fminf(mn[6], e6); mn[7] = fminf(mn[7], e7);
        }
        int c = 4;
        while (c < dg) {  // overflow (deg>4)
            int id[4];
#pragma unroll
            for (int k = 0; k < 4; k++) { int o = c + k; o = o > mV ? mV : o; id[k] = ci[sV + o]; }
#pragma unroll
            for (int k = 0; k < 4; k++) {
                float a0 = verts[3 * id[k]], a1 = verts[3 * id[k] + 1], a2 = verts[3 * id[k] + 2];
                float e0 = lrelu(bva.x + a0 * w0a.x + a1 * w1a.x + a2 * w2a.x);
                float e1 = lrelu(bva.y + a0 * w0a.y + a1 * w1a.y + a2 * w2a.y);
                float e2 = lrelu(bva.z + a0 * w0a.z + a1 * w1a.z + a2 * w2a.z);
                float e3 = lrelu(bva.w + a0 * w0a.w + a1 * w1a.w + a2 * w2a.w);
                float e4 = lrelu(bvb.x + a0 * w0b.x + a1 * w1b.x + a2 * w2b.x);
                float e5 = lrelu(bvb.y + a0 * w0b.y + a1 * w1b.y + a2 * w2b.y);
                float e6 = lrelu(bvb.z + a0 * w0b.z + a1 * w1b.z + a2 * w2b.z);
                float e7 = lrelu(bvb.w + a0 * w0b.w + a1 * w1b.w + a2 * w2b.w);
                mn[0] = fminf(mn[0], e0); mn[1] = fminf(mn[1], e1);
                mn[2] = fminf(mn[2], e2); mn[3] = fminf(mn[3], e3);
                mn[4] = fminf(mn[4], e4); mn[5] = fminf(mn[5], e5);
                mn[6] = fminf(mn[6], e6); mn[7] = fminf(mn[7], e7);
            }
            c += 4;
        }
        float m0 = dg ? lo16(xdv.x) - mn[0] : 0.f, m1 = dg ? hi16(xdv.x) - mn[1] : 0.f;
        float m2 = dg ? lo16(xdv.y) - mn[2] : 0.f, m3 = dg ? hi16(xdv.y) - mn[3] : 0.f;
        float m4 = dg ? lo16(xdv.z) - mn[4] : 0.f, m5 = dg ? hi16(xdv.z) - mn[5] : 0.f;
        float m6 = dg ? lo16(xdv.w) - mn[6] : 0.f, m7 = dg ? hi16(xdv.w) - mn[7] : 0.f;
        uint4 mxp = make_uint4(pack2bf(m0, m1), pack2bf(m2, m3), pack2bf(m4, m5), pack2bf(m6, m7));
        int r = rbase + rr;
        *(uint4*)&h[r * 264 + li16 * 8] = xdv;
        *(uint4*)&h[r * 264 + 128 + li16 * 8] = mxp;
    }
    __syncthreads();
    mlp_epilogue<false>(h, Wt, bias, x_eb, nullptr, r0, n_dst, wave, lane, t);
}

static inline char* alignp(char* p, size_t a) {
    return (char*)(((uintptr_t)p + a - 1) & ~(uintptr_t)(a - 1));
}

extern "C" void kernel_launch(void* const* d_in, const int* in_sizes, int n_in,
                              void* d_out, int out_size, void* d_ws, size_t ws_size,
                              hipStream_t stream) {
    const float* vertices = (const float*)d_in[0];
    const float* edges    = (const float*)d_in[1];
    const float* faces    = (const float*)d_in[2];
    const int* etv_v   = (const int*)d_in[3];
    const int* etv_e   = (const int*)d_in[4];
    const int* fte_e   = (const int*)d_in[5];
    const int* fte_f   = (const int*)d_in[6];
    const int* ftf_src = (const int*)d_in[7];
    const int* ftf_dst = (const int*)d_in[8];
    const float* Wv   = (const float*)d_in[9];
    const float* bv   = (const float*)d_in[10];
    const float* We   = (const float*)d_in[11];
    const float* be   = (const float*)d_in[12];
    const float* Wf   = (const float*)d_in[13];
    const float* bf_  = (const float*)d_in[14];
    const float* Wv2e = (const float*)d_in[15];
    const float* bv2e = (const float*)d_in[16];
    const float* We2f = (const float*)d_in[17];
    const float* be2f = (const float*)d_in[18];
    const float* Wm0  = (const float*)d_in[19];
    const float* bm0  = (const float*)d_in[20];
    const float* Wm1  = (const float*)d_in[21];
    const float* bm1  = (const float*)d_in[22];

    const int NV = in_sizes[0] / 3;
    const int NE = in_sizes[1] / 12;
    const int NF = in_sizes[2] / 14;
    const int N_EV = in_sizes[3];
    const int N_FE = in_sizes[5];
    const int N_FF = in_sizes[7];
    (void)NV; (void)n_in; (void)out_size; (void)ws_size;

    const int D = NE + NF + NF;
    const int NP = N_EV + N_FE + N_FF;
    const int NB = (D + BSZ - 1) >> BSHIFT;

    // ---- ws layout ----
    char* p = (char*)d_ws;
    unsigned short* x_eb = (unsigned short*)p;  p += (size_t)NE * W * sizeof(unsigned short);
    unsigned short* f0b  = (unsigned short*)p;  p += (size_t)NF * W * sizeof(unsigned short);
    unsigned short* f1b  = (unsigned short*)p;  p += (size_t)NF * W * sizeof(unsigned short);
    p = alignp(p, 16);
    int2* pairs = (int2*)p;                     p += (size_t)NP * sizeof(int2);
    int* ci     = (int*)p;                      p += (size_t)(NP + 8) * sizeof(int);
    int* rowptr = (int*)p;                      p += (size_t)(D + 1) * sizeof(int);
    int* gcnt   = (int*)p;                      p += 512 * sizeof(int);
    int* goff   = (int*)p;                      p += 513 * sizeof(int);
    int* gcur   = (int*)p;                      p += 512 * sizeof(int);
    p = alignp(p, 16);
    unsigned short* Wt0 = (unsigned short*)p;   p += (size_t)32768 * sizeof(unsigned short);
    unsigned short* Wt1 = (unsigned short*)p;   p += (size_t)32768 * sizeof(unsigned short);
    unsigned short* Wt2 = (unsigned short*)p;   p += (size_t)32768 * sizeof(unsigned short);
    unsigned short* Wt3 = (unsigned short*)p;   p += (size_t)32768 * sizeof(unsigned short);

    float* out_f = (float*)d_out;
    const int TB = 256;

    PairSrc P = {etv_e, etv_v, N_EV, fte_f, fte_e, N_FE, ftf_dst, ftf_src, N_FF, NE, NF};
    (void)hipMemsetAsync(gcnt, 0, 512 * sizeof(int), stream);

    // ---- prep: weight convert + part_hist (embeds now fused into convs) ----
    int gh = (NP + CHUNK - 1) / CHUNK;
    prep_kernel<<<512 + gh, TB, 0, stream>>>(Wv2e, We2f, Wm0, Wm1, Wt0, Wt1, Wt2, Wt3, P, gcnt);

    // ---- CSR build ----
    bucket_scan<<<1, 512, 0, stream>>>(gcnt, goff, gcur, NB, NP);
    part_scatter<<<gh, TB, 0, stream>>>(P, gcur, pairs);
    bucket_sort<<<NB, TB, 0, stream>>>(pairs, goff, D, NP, rowptr, ci);

    // ---- fused convs (embeds computed in-kernel on the dst path) ----
    fused_conv_v2e_rp<<<(NE + ROWS - 1) / ROWS, TB, 0, stream>>>(
        vertices, Wv, bv, edges, We, be, x_eb, rowptr, ci, Wt0, bv2e, NE);
    fused_conv_rp<14, false><<<(NF + ROWS - 1) / ROWS, TB, 0, stream>>>(
        x_eb, nullptr, faces, Wf, bf_, f0b, nullptr, rowptr + NE, ci, Wt1, be2f, NF);
    fused_conv_rp<0, false><<<(NF + ROWS - 1) / ROWS, TB, 0, stream>>>(
        f0b, f0b, nullptr, nullptr, nullptr, f1b, nullptr, rowptr + NE + NF, ci, Wt2, bm0, NF);
    fused_conv_rp<0, true><<<(NF + ROWS - 1) / ROWS, TB, 0, stream>>>(
        f1b, f1b, nullptr, nullptr, nullptr, nullptr, out_f, rowptr + NE + NF, ci, Wt3, bm1, NF);
}

// Round 9
// 581.180 us; speedup vs baseline: 2.6625x; 2.6625x over previous
//
#include <hip/hip_runtime.h>

#define W 128
#define ROWS 32      // dst rows per block in fused_conv
#define BSHIFT 10    // 1024 dst ids per bucket
#define BSZ 1024

typedef short bf16x8 __attribute__((ext_vector_type(8)));
typedef float f32x4 __attribute__((ext_vector_type(4)));

__device__ __forceinline__ float lrelu(float x) { return x > 0.f ? x : 0.01f * x; }

// RTNE float -> bf16 (as ushort bit pattern)
__device__ __forceinline__ unsigned short f2bf(float f) {
    unsigned u = __float_as_uint(f);
    u += 0x7fffu + ((u >> 16) & 1u);
    return (unsigned short)(u >> 16);
}
__device__ __forceinline__ float bfu(unsigned short u) {
    return __uint_as_float(((unsigned)u) << 16);
}
// dword-level bf16 pair unpack: 1 VALU per channel
__device__ __forceinline__ float lo16(unsigned u) { return __uint_as_float(u << 16); }
__device__ __forceinline__ float hi16(unsigned u) { return __uint_as_float(u & 0xffff0000u); }
__device__ __forceinline__ unsigned pack2bf(float lo, float hi) {
    return (unsigned)f2bf(lo) | ((unsigned)f2bf(hi) << 16);
}
// unpack 8 bf16 channels from uint4 and min-accumulate
__device__ __forceinline__ void upmin8(float* mn, uint4 u) {
    mn[0] = fminf(mn[0], lo16(u.x)); mn[1] = fminf(mn[1], hi16(u.x));
    mn[2] = fminf(mn[2], lo16(u.y)); mn[3] = fminf(mn[3], hi16(u.y));
    mn[4] = fminf(mn[4], lo16(u.z)); mn[5] = fminf(mn[5], hi16(u.z));
    mn[6] = fminf(mn[6], lo16(u.w)); mn[7] = fminf(mn[7], hi16(u.w));
}

// ---- bucket-partitioned CSR build over concatenated dst domain ----
struct PairSrc {
    const int* d0; const int* s0; int n0;
    const int* d1; const int* s1; int n1;
    const int* d2; const int* s2; int n2;
    int NE, NF;
};

__device__ __forceinline__ void pair_at(const PairSrc& P, int g, int& dp, int& sp) {
    dp = -1; sp = 0;
    if (g < P.n0) { dp = P.d0[g]; sp = P.s0[g]; }
    else if (g < P.n0 + P.n1) { int j = g - P.n0; dp = P.NE + P.d1[j]; sp = P.s1[j]; }
    else if (g < P.n0 + P.n1 + P.n2) { int j = g - P.n0 - P.n1; dp = P.NE + P.NF + P.d2[j]; sp = P.s2[j]; }
}
// dst-only variant (halves part_hist read traffic)
__device__ __forceinline__ int pair_d(const PairSrc& P, int g) {
    if (g < P.n0) return P.d0[g];
    if (g < P.n0 + P.n1) return P.NE + P.d1[g - P.n0];
    if (g < P.n0 + P.n1 + P.n2) return P.NE + P.NF + P.d2[g - P.n0 - P.n1];
    return -1;
}

#define CHUNK 4096

// =====================================================================
// prep kernel, block ranges:
//   [0, ge)       : edge embed, 16 rows/block, 8 ch/lane, weights in LDS
//   [ge, ge+gf)   : face embed, same scheme
//   [.., +512)    : 4x weight convert fp32[256][128] -> bf16 T[128][256]
//   [.., +gh)     : part_hist (dst-only reads)
// Embed scheme: thread t covers row rb*16+(t>>4), channels (t&15)*8..+8.
// K scalar row loads (broadcast within 16-lane group, L1) + K*2 LDS
// float4 reads + K*8 FMA -> one coalesced uint4 store. ~8x fewer VMEM
// instructions than the 1-ch/thread version (round-6 prep, 150us).
// =====================================================================
__global__ __launch_bounds__(256) void prep_kernel(
    const float* __restrict__ edges, const float* __restrict__ We, const float* __restrict__ be,
    unsigned short* __restrict__ x_eb, int NE,
    const float* __restrict__ faces, const float* __restrict__ Wf, const float* __restrict__ bfc,
    unsigned short* __restrict__ f0b, int NF,
    const float* __restrict__ W0, const float* __restrict__ W1,
    const float* __restrict__ W2, const float* __restrict__ W3,
    unsigned short* __restrict__ T0, unsigned short* __restrict__ T1,
    unsigned short* __restrict__ T2, unsigned short* __restrict__ T3,
    PairSrc P, int* __restrict__ gcnt, int ge, int gf) {
    __shared__ float wl[14 * W];
    __shared__ float bl[W];
    __shared__ int hist[512];
    int b = blockIdx.x, t = threadIdx.x;
    if (b < ge + gf) {  // embeds
        const float* in; const float* Wm; const float* bb; unsigned short* ob;
        int n, K, rb;
        if (b < ge) { in = edges; Wm = We; bb = be; ob = x_eb; n = NE; K = 12; rb = b; }
        else        { in = faces; Wm = Wf; bb = bfc; ob = f0b; n = NF; K = 14; rb = b - ge; }
        for (int i = t; i < K * W; i += 256) wl[i] = Wm[i];
        if (t < W) bl[t] = bb[t];
        __syncthreads();
        int g = t >> 4, li = t & 15;
        int row = rb * 16 + g;
        if (row >= n) return;
        int ch0 = li * 8;
        float s[8];
#pragma unroll
        for (int j = 0; j < 8; j++) s[j] = bl[ch0 + j];
        for (int k = 0; k < K; k++) {
            float rv = in[(size_t)row * K + k];
            float4 wa = *(const float4*)&wl[k * W + ch0];
            float4 wb = *(const float4*)&wl[k * W + ch0 + 4];
            s[0] += rv * wa.x; s[1] += rv * wa.y; s[2] += rv * wa.z; s[3] += rv * wa.w;
            s[4] += rv * wb.x; s[5] += rv * wb.y; s[6] += rv * wb.z; s[7] += rv * wb.w;
        }
        uint4 o = make_uint4(pack2bf(lrelu(s[0]), lrelu(s[1])), pack2bf(lrelu(s[2]), lrelu(s[3])),
                             pack2bf(lrelu(s[4]), lrelu(s[5])), pack2bf(lrelu(s[6]), lrelu(s[7])));
        ((uint4*)ob)[(size_t)row * 16 + li] = o;
    } else if (b < ge + gf + 512) {  // weight convert
        int wb = b - ge - gf;
        int which = wb >> 7;
        const float* Wm = (which == 0) ? W0 : (which == 1) ? W1 : (which == 2) ? W2 : W3;
        unsigned short* Wt = (which == 0) ? T0 : (which == 1) ? T1 : (which == 2) ? T2 : T3;
        int i = (wb & 127) * 256 + t;
        int k = i >> 7, n = i & 127;
        Wt[n * 256 + k] = f2bf(Wm[k * W + n]);
    } else {  // part_hist (dst-only reads)
        int hb = b - ge - gf - 512;
        for (int j = t; j < 512; j += 256) hist[j] = 0;
        __syncthreads();
        int g0 = hb * CHUNK;
#pragma unroll
        for (int k = 0; k < 16; k++) {
            int dp = pair_d(P, g0 + k * 256 + t);
            if (dp >= 0) atomicAdd(&hist[dp >> BSHIFT], 1);
        }
        __syncthreads();
        for (int j = t; j < 512; j += 256)
            if (hist[j]) atomicAdd(&gcnt[j], hist[j]);
    }
}

__global__ void bucket_scan(const int* __restrict__ gcnt, int* __restrict__ goff,
                            int* __restrict__ gcur, int NB, int NP) {
    __shared__ int s[512];
    int t = threadIdx.x;
    int v = (t < NB) ? gcnt[t] : 0;
    s[t] = v;
    __syncthreads();
    for (int off = 1; off < 512; off <<= 1) {
        int add = (t >= off) ? s[t - off] : 0;
        __syncthreads();
        s[t] += add;
        __syncthreads();
    }
    if (t < NB) {
        int excl = s[t] - v;
        goff[t] = excl;
        gcur[t] = excl;
    }
    if (t == 0) goff[NB] = NP;
}

__global__ __launch_bounds__(256) void part_scatter(PairSrc P, int* __restrict__ gcur,
                                                    int2* __restrict__ pairs) {
    __shared__ int hist[512];
    __shared__ int base[512];
    int t = threadIdx.x;
    for (int j = t; j < 512; j += 256) hist[j] = 0;
    __syncthreads();
    int g0 = blockIdx.x * CHUNK;
    int dv[16], sv[16], rk[16];
#pragma unroll
    for (int k = 0; k < 16; k++) {
        pair_at(P, g0 + k * 256 + t, dv[k], sv[k]);
        rk[k] = (dv[k] >= 0) ? atomicAdd(&hist[dv[k] >> BSHIFT], 1) : 0;
    }
    __syncthreads();
    for (int j = t; j < 512; j += 256)
        base[j] = hist[j] ? atomicAdd(&gcur[j], hist[j]) : 0;
    __syncthreads();
#pragma unroll
    for (int k = 0; k < 16; k++) {
        if (dv[k] >= 0) pairs[base[dv[k] >> BSHIFT] + rk[k]] = make_int2(dv[k], sv[k]);
    }
}

// one block per bucket: LDS counting sort -> rowptr + ci (src only)
__global__ __launch_bounds__(256) void bucket_sort(const int2* __restrict__ pairs,
                                                   const int* __restrict__ goff, int D, int NP,
                                                   int* __restrict__ rowptr,
                                                   int* __restrict__ ci) {
    __shared__ int hist[BSZ];
    __shared__ int base[BSZ];
    __shared__ int tsum[256];
    int b = blockIdx.x, t = threadIdx.x;
    int d0 = b << BSHIFT;
    int roff = goff[b], rend = goff[b + 1], cnt = rend - roff;
    for (int j = t; j < BSZ; j += 256) hist[j] = 0;
    __syncthreads();
    for (int i = t; i < cnt; i += 256) {
        int2 pr = pairs[roff + i];
        atomicAdd(&hist[pr.x - d0], 1);
    }
    __syncthreads();
    int loc[4], s0 = 0;
#pragma unroll
    for (int k = 0; k < 4; k++) {
        loc[k] = s0;
        s0 += hist[t * 4 + k];
    }
    tsum[t] = s0;
    __syncthreads();
    for (int off = 1; off < 256; off <<= 1) {
        int add = (t >= off) ? tsum[t - off] : 0;
        __syncthreads();
        tsum[t] += add;
        __syncthreads();
    }
    int ebase = tsum[t] - s0;
#pragma unroll
    for (int k = 0; k < 4; k++) base[t * 4 + k] = ebase + loc[k];
    __syncthreads();
    for (int j = t; j < BSZ; j += 256) {
        int d = d0 + j;
        if (d < D) rowptr[d] = roff + base[j];
    }
    if (b == 0 && t == 0) rowptr[D] = NP;
    if (b == 0 && t < 8) ci[NP + t] = 0;  // zero pad: clamped prefetch beyond NP is safe
    for (int j = t; j < BSZ; j += 256) hist[j] = base[j];
    __syncthreads();
    for (int i = t; i < cnt; i += 256) {
        int2 pr = pairs[roff + i];
        int pos = roff + atomicAdd(&hist[pr.x - d0], 1);
        ci[pos] = pr.y;
    }
}

// ---- shared MFMA MLP + residual epilogue; output staged in LDS for
//      fully-coalesced 16B-lane stores ----
template <bool OUT_F32>
__device__ __forceinline__ void mlp_epilogue(
    unsigned short* h, const unsigned short* __restrict__ Wt,
    const float* __restrict__ bias, unsigned short* __restrict__ out_b,
    float* __restrict__ out_f, int r0, int n_dst, int wave, int lane, int tid) {
    int rt = wave >> 1;
    int ctbase = (wave & 1) * 4;
    int m = lane & 15, q = lane >> 4;
    f32x4 acc[4];
#pragma unroll
    for (int ct = 0; ct < 4; ct++) acc[ct] = (f32x4){0.f, 0.f, 0.f, 0.f};
    for (int k0 = 0; k0 < 256; k0 += 32) {
        bf16x8 a = *(const bf16x8*)&h[(rt * 16 + m) * 264 + k0 + q * 8];
#pragma unroll
        for (int ct = 0; ct < 4; ct++) {
            int n = (ctbase + ct) * 16 + m;
            bf16x8 b = *(const bf16x8*)&Wt[n * 256 + k0 + q * 8];
            acc[ct] = __builtin_amdgcn_mfma_f32_16x16x32_bf16(a, b, acc[ct], 0, 0, 0);
        }
    }
    // residual + activation into acc (reads h; no h writes yet)
#pragma unroll
    for (int ct = 0; ct < 4; ct++) {
        int col = (ctbase + ct) * 16 + m;
        float bc = bias[col];
#pragma unroll
        for (int reg = 0; reg < 4; reg++) {
            int r_l = rt * 16 + q * 4 + reg;
            acc[ct][reg] = bfu(h[r_l * 264 + col]) + lrelu(acc[ct][reg] + bc);
        }
    }
    __syncthreads();  // all reads of h complete
    if (OUT_F32) {
        float* hf = (float*)h;  // compact [32][128] f32 tile
#pragma unroll
        for (int ct = 0; ct < 4; ct++) {
            int col = (ctbase + ct) * 16 + m;
#pragma unroll
            for (int reg = 0; reg < 4; reg++) {
                int r_l = rt * 16 + q * 4 + reg;
                hf[r_l * 128 + col] = acc[ct][reg];
            }
        }
    } else {
        unsigned short* hs = h;  // compact [32][128] bf16 tile
#pragma unroll
        for (int ct = 0; ct < 4; ct++) {
            int col = (ctbase + ct) * 16 + m;
#pragma unroll
            for (int reg = 0; reg < 4; reg++) {
                int r_l = rt * 16 + q * 4 + reg;
                hs[r_l * 128 + col] = f2bf(acc[ct][reg]);
            }
        }
    }
    __syncthreads();
    if (OUT_F32) {
        const uint4* hv = (const uint4*)h;  // 32 rows x 32 uint4
        for (int i = tid; i < 1024; i += 256) {
            int r_l = i >> 5;
            int row = r0 + r_l;
            if (row < n_dst) ((uint4*)out_f)[(size_t)row * 32 + (i & 31)] = hv[i];
        }
    } else {
        const uint4* hv = (const uint4*)h;  // 32 rows x 16 uint4
        for (int i = tid; i < 512; i += 256) {
            int r_l = i >> 4;
            int row = r0 + r_l;
            if (row < n_dst) ((uint4*)out_b)[(size_t)row * 16 + (i & 15)] = hv[i];
        }
    }
}

// =====================================================================
// fused conv, ROW-parallel: 16 groups of 16 lanes; each group owns 2 rows
// (A,B). All 16 window-1 gathers issued before any drain; VGPR budget
// raised via __launch_bounds__(256,4) (round-6 proven: no spill, convs
// fell out of the top-5 dispatches).
// =====================================================================
template <bool OUT_F32>
__global__ __launch_bounds__(256, 4) void fused_conv_rp(
    const unsigned short* __restrict__ xsb, const unsigned short* __restrict__ xdb,
    unsigned short* __restrict__ out_b, float* __restrict__ out_f,
    const int* __restrict__ rowptr, const int* __restrict__ ci,
    const unsigned short* __restrict__ Wt, const float* __restrict__ bias, int n_dst) {
    __shared__ unsigned short h[ROWS * 264];  // [32 rows][256 + 8 pad] bf16
    int t = threadIdx.x;
    int wave = t >> 6, lane = t & 63;
    int grp = t >> 4;        // 0..15, owns rows {2*grp, 2*grp+1}
    int li16 = t & 15;       // 16B slot within 256B row
    int r0 = blockIdx.x * ROWS;
    int rbase = grp * 2;
    const uint4* xs4 = (const uint4*)xsb;
    const uint4* xd4 = (const uint4*)xdb;

    int dA = r0 + rbase, dB = dA + 1;
    int sA = 0, dgA = 0, sB = 0, dgB = 0;
    if (dA < n_dst) { sA = rowptr[dA]; dgA = rowptr[dA + 1] - sA; }
    if (dB < n_dst) { sB = rowptr[dB]; dgB = rowptr[dB + 1] - sB; }
    int mA = dgA - 1; if (mA < 0) mA = 0;
    int mB = dgB - 1; if (mB < 0) mB = 0;

    // window-1 indices for both rows (clamped; dup gathers hit L1)
    int idxA[8], idxB[8];
#pragma unroll
    for (int k = 0; k < 8; k++) { int o = k > mA ? mA : k; idxA[k] = ci[sA + o]; }
#pragma unroll
    for (int k = 0; k < 8; k++) { int o = k > mB ? mB : k; idxB[k] = ci[sB + o]; }

    // own rows (coalesced within group)
    uint4 xdvA = make_uint4(0, 0, 0, 0), xdvB = make_uint4(0, 0, 0, 0);
    if (dA < n_dst) xdvA = xd4[(size_t)dA * 16 + li16];
    if (dB < n_dst) xdvB = xd4[(size_t)dB * 16 + li16];

    // issue all 16 window-1 gathers before any consumption
    uint4 a0 = xs4[(size_t)idxA[0] * 16 + li16], a1 = xs4[(size_t)idxA[1] * 16 + li16];
    uint4 a2 = xs4[(size_t)idxA[2] * 16 + li16], a3 = xs4[(size_t)idxA[3] * 16 + li16];
    uint4 a4 = xs4[(size_t)idxA[4] * 16 + li16], a5 = xs4[(size_t)idxA[5] * 16 + li16];
    uint4 a6 = xs4[(size_t)idxA[6] * 16 + li16], a7 = xs4[(size_t)idxA[7] * 16 + li16];
    uint4 b0 = xs4[(size_t)idxB[0] * 16 + li16], b1 = xs4[(size_t)idxB[1] * 16 + li16];
    uint4 b2 = xs4[(size_t)idxB[2] * 16 + li16], b3 = xs4[(size_t)idxB[3] * 16 + li16];
    uint4 b4 = xs4[(size_t)idxB[4] * 16 + li16], b5 = xs4[(size_t)idxB[5] * 16 + li16];
    uint4 b6 = xs4[(size_t)idxB[6] * 16 + li16], b7 = xs4[(size_t)idxB[7] * 16 + li16];

    // window-2 indices prefetch (only used if deg>8; clamp keeps them safe)
    int idxA2[8], idxB2[8];
#pragma unroll
    for (int k = 0; k < 8; k++) { int o = 8 + k; o = o > mA ? mA : o; idxA2[k] = ci[sA + o]; }
#pragma unroll
    for (int k = 0; k < 8; k++) { int o = 8 + k; o = o > mB ? mB : o; idxB2[k] = ci[sB + o]; }

    // ---- reduce row A
    {
        float mn[8];
#pragma unroll
        for (int k = 0; k < 8; k++) mn[k] = 1e30f;
        upmin8(mn, a0); upmin8(mn, a1); upmin8(mn, a2); upmin8(mn, a3);
        upmin8(mn, a4); upmin8(mn, a5); upmin8(mn, a6); upmin8(mn, a7);
        if (dgA > 8) {
            uint4 v0 = xs4[(size_t)idxA2[0] * 16 + li16], v1 = xs4[(size_t)idxA2[1] * 16 + li16];
            uint4 v2 = xs4[(size_t)idxA2[2] * 16 + li16], v3 = xs4[(size_t)idxA2[3] * 16 + li16];
            uint4 v4 = xs4[(size_t)idxA2[4] * 16 + li16], v5 = xs4[(size_t)idxA2[5] * 16 + li16];
            uint4 v6 = xs4[(size_t)idxA2[6] * 16 + li16], v7 = xs4[(size_t)idxA2[7] * 16 + li16];
            upmin8(mn, v0); upmin8(mn, v1); upmin8(mn, v2); upmin8(mn, v3);
            upmin8(mn, v4); upmin8(mn, v5); upmin8(mn, v6); upmin8(mn, v7);
            int c = 16;
            while (c < dgA) {  // rare (deg>16)
                int id[8];
#pragma unroll
                for (int k = 0; k < 8; k++) { int o = c + k; o = o > mA ? mA : o; id[k] = ci[sA + o]; }
                uint4 w0 = xs4[(size_t)id[0] * 16 + li16], w1 = xs4[(size_t)id[1] * 16 + li16];
                uint4 w2 = xs4[(size_t)id[2] * 16 + li16], w3 = xs4[(size_t)id[3] * 16 + li16];
                uint4 w4 = xs4[(size_t)id[4] * 16 + li16], w5 = xs4[(size_t)id[5] * 16 + li16];
                uint4 w6 = xs4[(size_t)id[6] * 16 + li16], w7 = xs4[(size_t)id[7] * 16 + li16];
                upmin8(mn, w0); upmin8(mn, w1); upmin8(mn, w2); upmin8(mn, w3);
                upmin8(mn, w4); upmin8(mn, w5); upmin8(mn, w6); upmin8(mn, w7);
                c += 8;
            }
        }
        float m0 = dgA ? lo16(xdvA.x) - mn[0] : 0.f, m1 = dgA ? hi16(xdvA.x) - mn[1] : 0.f;
        float m2 = dgA ? lo16(xdvA.y) - mn[2] : 0.f, m3 = dgA ? hi16(xdvA.y) - mn[3] : 0.f;
        float m4 = dgA ? lo16(xdvA.z) - mn[4] : 0.f, m5 = dgA ? hi16(xdvA.z) - mn[5] : 0.f;
        float m6 = dgA ? lo16(xdvA.w) - mn[6] : 0.f, m7 = dgA ? hi16(xdvA.w) - mn[7] : 0.f;
        uint4 mxp = make_uint4(pack2bf(m0, m1), pack2bf(m2, m3), pack2bf(m4, m5), pack2bf(m6, m7));
        *(uint4*)&h[rbase * 264 + li16 * 8] = xdvA;
        *(uint4*)&h[rbase * 264 + 128 + li16 * 8] = mxp;
    }
    // ---- reduce row B
    {
        float mn[8];
#pragma unroll
        for (int k = 0; k < 8; k++) mn[k] = 1e30f;
        upmin8(mn, b0); upmin8(mn, b1); upmin8(mn, b2); upmin8(mn, b3);
        upmin8(mn, b4); upmin8(mn, b5); upmin8(mn, b6); upmin8(mn, b7);
        if (dgB > 8) {
            uint4 v0 = xs4[(size_t)idxB2[0] * 16 + li16], v1 = xs4[(size_t)idxB2[1] * 16 + li16];
            uint4 v2 = xs4[(size_t)idxB2[2] * 16 + li16], v3 = xs4[(size_t)idxB2[3] * 16 + li16];
            uint4 v4 = xs4[(size_t)idxB2[4] * 16 + li16], v5 = xs4[(size_t)idxB2[5] * 16 + li16];
            uint4 v6 = xs4[(size_t)idxB2[6] * 16 + li16], v7 = xs4[(size_t)idxB2[7] * 16 + li16];
            upmin8(mn, v0); upmin8(mn, v1); upmin8(mn, v2); upmin8(mn, v3);
            upmin8(mn, v4); upmin8(mn, v5); upmin8(mn, v6); upmin8(mn, v7);
            int c = 16;
            while (c < dgB) {
                int id[8];
#pragma unroll
                for (int k = 0; k < 8; k++) { int o = c + k; o = o > mB ? mB : o; id[k] = ci[sB + o]; }
                uint4 w0 = xs4[(size_t)id[0] * 16 + li16], w1 = xs4[(size_t)id[1] * 16 + li16];
                uint4 w2 = xs4[(size_t)id[2] * 16 + li16], w3 = xs4[(size_t)id[3] * 16 + li16];
                uint4 w4 = xs4[(size_t)id[4] * 16 + li16], w5 = xs4[(size_t)id[5] * 16 + li16];
                uint4 w6 = xs4[(size_t)id[6] * 16 + li16], w7 = xs4[(size_t)id[7] * 16 + li16];
                upmin8(mn, w0); upmin8(mn, w1); upmin8(mn, w2); upmin8(mn, w3);
                upmin8(mn, w4); upmin8(mn, w5); upmin8(mn, w6); upmin8(mn, w7);
                c += 8;
            }
        }
        float m0 = dgB ? lo16(xdvB.x) - mn[0] : 0.f, m1 = dgB ? hi16(xdvB.x) - mn[1] : 0.f;
        float m2 = dgB ? lo16(xdvB.y) - mn[2] : 0.f, m3 = dgB ? hi16(xdvB.y) - mn[3] : 0.f;
        float m4 = dgB ? lo16(xdvB.z) - mn[4] : 0.f, m5 = dgB ? hi16(xdvB.z) - mn[5] : 0.f;
        float m6 = dgB ? lo16(xdvB.w) - mn[6] : 0.f, m7 = dgB ? hi16(xdvB.w) - mn[7] : 0.f;
        uint4 mxp = make_uint4(pack2bf(m0, m1), pack2bf(m2, m3), pack2bf(m4, m5), pack2bf(m6, m7));
        *(uint4*)&h[(rbase + 1) * 264 + li16 * 8] = xdvB;
        *(uint4*)&h[(rbase + 1) * 264 + 128 + li16 * 8] = mxp;
    }
    __syncthreads();
    mlp_epilogue<OUT_F32>(h, Wt, bias, out_b, out_f, r0, n_dst, wave, lane, t);
}

// =====================================================================
// V2E conv: gather RAW 12B vertices (L2-resident table) and compute the
// src embed in-register; dst = x_eb (materialized by prep). Round-6
// proven structure (no spill).
// =====================================================================
__global__ __launch_bounds__(256, 4) void fused_conv_v2e_rp(
    const float* __restrict__ verts, const float* __restrict__ Wv, const float* __restrict__ bv,
    unsigned short* __restrict__ x_eb, const int* __restrict__ rowptr,
    const int* __restrict__ ci,
    const unsigned short* __restrict__ Wt, const float* __restrict__ bias, int n_dst) {
    __shared__ unsigned short h[ROWS * 264];
    int t = threadIdx.x;
    int wave = t >> 6, lane = t & 63;
    int grp = t >> 4;
    int li16 = t & 15;
    int r0 = blockIdx.x * ROWS;
    int rbase = grp * 2;
    const uint4* xd4 = (const uint4*)x_eb;

    // this lane's 8-channel slice of the vertex embed weights
    float4 w0a = *(const float4*)&Wv[0 * W + li16 * 8], w0b = *(const float4*)&Wv[0 * W + li16 * 8 + 4];
    float4 w1a = *(const float4*)&Wv[1 * W + li16 * 8], w1b = *(const float4*)&Wv[1 * W + li16 * 8 + 4];
    float4 w2a = *(const float4*)&Wv[2 * W + li16 * 8], w2b = *(const float4*)&Wv[2 * W + li16 * 8 + 4];
    float4 bva = *(const float4*)&bv[li16 * 8],         bvb = *(const float4*)&bv[li16 * 8 + 4];

    int dA = r0 + rbase, dB = dA + 1;
    int sA = 0, dgA = 0, sB = 0, dgB = 0;
    if (dA < n_dst) { sA = rowptr[dA]; dgA = rowptr[dA + 1] - sA; }
    if (dB < n_dst) { sB = rowptr[dB]; dgB = rowptr[dB + 1] - sB; }
    int mA = dgA - 1; if (mA < 0) mA = 0;
    int mB = dgB - 1; if (mB < 0) mB = 0;

    int idxA[4], idxB[4];
#pragma unroll
    for (int k = 0; k < 4; k++) { int o = k > mA ? mA : k; idxA[k] = ci[sA + o]; }
#pragma unroll
    for (int k = 0; k < 4; k++) { int o = k > mB ? mB : k; idxB[k] = ci[sB + o]; }

    uint4 xdvA = make_uint4(0, 0, 0, 0), xdvB = make_uint4(0, 0, 0, 0);
    if (dA < n_dst) xdvA = xd4[(size_t)dA * 16 + li16];
    if (dB < n_dst) xdvB = xd4[(size_t)dB * 16 + li16];

    // issue all vertex loads for both windows (broadcast within group)
    float vA[4][3], vB[4][3];
#pragma unroll
    for (int k = 0; k < 4; k++) {
        vA[k][0] = verts[3 * idxA[k]]; vA[k][1] = verts[3 * idxA[k] + 1]; vA[k][2] = verts[3 * idxA[k] + 2];
    }
#pragma unroll
    for (int k = 0; k < 4; k++) {
        vB[k][0] = verts[3 * idxB[k]]; vB[k][1] = verts[3 * idxB[k] + 1]; vB[k][2] = verts[3 * idxB[k] + 2];
    }

#pragma unroll
    for (int rr = 0; rr < 2; rr++) {
        int dg = (rr == 0) ? dgA : dgB;
        int sV = (rr == 0) ? sA : sB;
        int mV = (rr == 0) ? mA : mB;
        uint4 xdv = (rr == 0) ? xdvA : xdvB;
        float mn[8];
#pragma unroll
        for (int k = 0; k < 8; k++) mn[k] = 1e30f;
#pragma unroll
        for (int k = 0; k < 4; k++) {
            float a0 = (rr == 0) ? vA[k][0] : vB[k][0];
            float a1 = (rr == 0) ? vA[k][1] : vB[k][1];
            float a2 = (rr == 0) ? vA[k][2] : vB[k][2];
            float e0 = lrelu(bva.x + a0 * w0a.x + a1 * w1a.x + a2 * w2a.x);
            float e1 = lrelu(bva.y + a0 * w0a.y + a1 * w1a.y + a2 * w2a.y);
            float e2 = lrelu(bva.z + a0 * w0a.z + a1 * w1a.z + a2 * w2a.z);
            float e3 = lrelu(bva.w + a0 * w0a.w + a1 * w1a.w + a2 * w2a.w);
            float e4 = lrelu(bvb.x + a0 * w0b.x + a1 * w1b.x + a2 * w2b.x);
            float e5 = lrelu(bvb.y + a0 * w0b.y + a1 * w1b.y + a2 * w2b.y);
            float e6 = lrelu(bvb.z + a0 * w0b.z + a1 * w1b.z + a2 * w2b.z);
            float e7 = lrelu(bvb.w + a0 * w0b.w + a1 * w1b.w + a2 * w2b.w);
            mn[0] = fminf(mn[0], e0); mn[1] = fminf(mn[1], e1);
            mn[2] = fminf(mn[2], e2); mn[3] = fminf(mn[3], e3);
            mn[4] = fminf(mn[4], e4); mn[5] = fminf(mn[5], e5);
            mn[6] = fminf(mn[6], e6); mn[7] = fminf(mn[7], e7);
        }
        int c = 4;
        while (c < dg) {  // overflow (deg>4)
            int id[4];
#pragma unroll
            for (int k = 0; k < 4; k++) { int o = c + k; o = o > mV ? mV : o; id[k] = ci[sV + o]; }
#pragma unroll
            for (int k = 0; k < 4; k++) {
                float a0 = verts[3 * id[k]], a1 = verts[3 * id[k] + 1], a2 = verts[3 * id[k] + 2];
                float e0 = lrelu(bva.x + a0 * w0a.x + a1 * w1a.x + a2 * w2a.x);
                float e1 = lrelu(bva.y + a0 * w0a.y + a1 * w1a.y + a2 * w2a.y);
                float e2 = lrelu(bva.z + a0 * w0a.z + a1 * w1a.z + a2 * w2a.z);
                float e3 = lrelu(bva.w + a0 * w0a.w + a1 * w1a.w + a2 * w2a.w);
                float e4 = lrelu(bvb.x + a0 * w0b.x + a1 * w1b.x + a2 * w2b.x);
                float e5 = lrelu(bvb.y + a0 * w0b.y + a1 * w1b.y + a2 * w2b.y);
                float e6 = lrelu(bvb.z + a0 * w0b.z + a1 * w1b.z + a2 * w2b.z);
                float e7 = lrelu(bvb.w + a0 * w0b.w + a1 * w1b.w + a2 * w2b.w);
                mn[0] = fminf(mn[0], e0); mn[1] = fminf(mn[1], e1);
                mn[2] = fminf(mn[2], e2); mn[3] = fminf(mn[3], e3);
                mn[4] = fminf(mn[4], e4); mn[5] = fminf(mn[5], e5);
                mn[6] = fminf(mn[6], e6); mn[7] = fminf(mn[7], e7);
            }
            c += 4;
        }
        float m0 = dg ? lo16(xdv.x) - mn[0] : 0.f, m1 = dg ? hi16(xdv.x) - mn[1] : 0.f;
        float m2 = dg ? lo16(xdv.y) - mn[2] : 0.f, m3 = dg ? hi16(xdv.y) - mn[3] : 0.f;
        float m4 = dg ? lo16(xdv.z) - mn[4] : 0.f, m5 = dg ? hi16(xdv.z) - mn[5] : 0.f;
        float m6 = dg ? lo16(xdv.w) - mn[6] : 0.f, m7 = dg ? hi16(xdv.w) - mn[7] : 0.f;
        uint4 mxp = make_uint4(pack2bf(m0, m1), pack2bf(m2, m3), pack2bf(m4, m5), pack2bf(m6, m7));
        int r = rbase + rr;
        *(uint4*)&h[r * 264 + li16 * 8] = xdv;
        *(uint4*)&h[r * 264 + 128 + li16 * 8] = mxp;
    }
    __syncthreads();
    mlp_epilogue<false>(h, Wt, bias, x_eb, nullptr, r0, n_dst, wave, lane, t);
}

static inline char* alignp(char* p, size_t a) {
    return (char*)(((uintptr_t)p + a - 1) & ~(uintptr_t)(a - 1));
}

extern "C" void kernel_launch(void* const* d_in, const int* in_sizes, int n_in,
                              void* d_out, int out_size, void* d_ws, size_t ws_size,
                              hipStream_t stream) {
    const float* vertices = (const float*)d_in[0];
    const float* edges    = (const float*)d_in[1];
    const float* faces    = (const float*)d_in[2];
    const int* etv_v   = (const int*)d_in[3];
    const int* etv_e   = (const int*)d_in[4];
    const int* fte_e   = (const int*)d_in[5];
    const int* fte_f   = (const int*)d_in[6];
    const int* ftf_src = (const int*)d_in[7];
    const int* ftf_dst = (const int*)d_in[8];
    const float* Wv   = (const float*)d_in[9];
    const float* bv   = (const float*)d_in[10];
    const float* We   = (const float*)d_in[11];
    const float* be   = (const float*)d_in[12];
    const float* Wf   = (const float*)d_in[13];
    const float* bf_  = (const float*)d_in[14];
    const float* Wv2e = (const float*)d_in[15];
    const float* bv2e = (const float*)d_in[16];
    const float* We2f = (const float*)d_in[17];
    const float* be2f = (const float*)d_in[18];
    const float* Wm0  = (const float*)d_in[19];
    const float* bm0  = (const float*)d_in[20];
    const float* Wm1  = (const float*)d_in[21];
    const float* bm1  = (const float*)d_in[22];

    const int NV = in_sizes[0] / 3;
    const int NE = in_sizes[1] / 12;
    const int NF = in_sizes[2] / 14;
    const int N_EV = in_sizes[3];
    const int N_FE = in_sizes[5];
    const int N_FF = in_sizes[7];
    (void)NV; (void)n_in; (void)out_size; (void)ws_size;

    const int D = NE + NF + NF;
    const int NP = N_EV + N_FE + N_FF;
    const int NB = (D + BSZ - 1) >> BSHIFT;

    // ---- ws layout ----
    char* p = (char*)d_ws;
    unsigned short* x_eb = (unsigned short*)p;  p += (size_t)NE * W * sizeof(unsigned short);
    unsigned short* f0b  = (unsigned short*)p;  p += (size_t)NF * W * sizeof(unsigned short);
    unsigned short* f1b  = (unsigned short*)p;  p += (size_t)NF * W * sizeof(unsigned short);
    p = alignp(p, 16);
    int2* pairs = (int2*)p;                     p += (size_t)NP * sizeof(int2);
    int* ci     = (int*)p;                      p += (size_t)(NP + 8) * sizeof(int);
    int* rowptr = (int*)p;                      p += (size_t)(D + 1) * sizeof(int);
    int* gcnt   = (int*)p;                      p += 512 * sizeof(int);
    int* goff   = (int*)p;                      p += 513 * sizeof(int);
    int* gcur   = (int*)p;                      p += 512 * sizeof(int);
    p = alignp(p, 16);
    unsigned short* Wt0 = (unsigned short*)p;   p += (size_t)32768 * sizeof(unsigned short);
    unsigned short* Wt1 = (unsigned short*)p;   p += (size_t)32768 * sizeof(unsigned short);
    unsigned short* Wt2 = (unsigned short*)p;   p += (size_t)32768 * sizeof(unsigned short);
    unsigned short* Wt3 = (unsigned short*)p;   p += (size_t)32768 * sizeof(unsigned short);

    float* out_f = (float*)d_out;
    const int TB = 256;

    PairSrc P = {etv_e, etv_v, N_EV, fte_f, fte_e, N_FE, ftf_dst, ftf_src, N_FF, NE, NF};
    (void)hipMemsetAsync(gcnt, 0, 512 * sizeof(int), stream);

    // ---- fused prep: embeds (16 rows/block, 8ch/lane) + wconv + part_hist ----
    int ge = (NE + 15) / 16, gf = (NF + 15) / 16;
    int gh = (NP + CHUNK - 1) / CHUNK;
    prep_kernel<<<ge + gf + 512 + gh, TB, 0, stream>>>(
        edges, We, be, x_eb, NE, faces, Wf, bf_, f0b, NF,
        Wv2e, We2f, Wm0, Wm1, Wt0, Wt1, Wt2, Wt3, P, gcnt, ge, gf);

    // ---- CSR build ----
    bucket_scan<<<1, 512, 0, stream>>>(gcnt, goff, gcur, NB, NP);
    part_scatter<<<gh, TB, 0, stream>>>(P, gcur, pairs);
    bucket_sort<<<NB, TB, 0, stream>>>(pairs, goff, D, NP, rowptr, ci);

    // ---- fused convs (round-6 proven) ----
    fused_conv_v2e_rp<<<(NE + ROWS - 1) / ROWS, TB, 0, stream>>>(
        vertices, Wv, bv, x_eb, rowptr, ci, Wt0, bv2e, NE);
    fused_conv_rp<false><<<(NF + ROWS - 1) / ROWS, TB, 0, stream>>>(
        x_eb, f0b, f0b, nullptr, rowptr + NE, ci, Wt1, be2f, NF);
    fused_conv_rp<false><<<(NF + ROWS - 1) / ROWS, TB, 0, stream>>>(
        f0b, f0b, f1b, nullptr, rowptr + NE + NF, ci, Wt2, bm0, NF);
    fused_conv_rp<true><<<(NF + ROWS - 1) / ROWS, TB, 0, stream>>>(
        f1b, f1b, nullptr, out_f, rowptr + NE + NF, ci, Wt3, bm1, NF);
}